// Round 2
// baseline (84.024 us; speedup 1.0000x reference)
//
#include <hip/hip_runtime.h>
#include <hip/hip_fp16.h>

// INT4 asymmetric weight decompressor.
// d_in[0] x:        33,554,432 int32, each holding 2 uint4 nibbles (low first)
// d_in[1] scale:    524,288 float32 (harness upcasts the reference's fp16;
//                   values are exactly fp16-representable)
// d_in[2] zp_packed: 262,144 int32, each holding 2 uint4 zero points (low first)
// d_out   out:      67,108,864 fp32 = (w - zp) * scale, rounded through fp16
//
// Each thread-iteration: 2 packed words -> 4 outputs (int2 load, float4 store).
//   group linear index gl = out_flat/128 = iter/32  (128 outputs per group)
//   zp word = zp[gl>>1], nibble (gl&1)

__global__ void __launch_bounds__(256)
int4_dequant_kernel(const int* __restrict__ x,
                    const float* __restrict__ scale,
                    const int* __restrict__ zp,
                    float* __restrict__ out,
                    int niter)
{
    const int stride = gridDim.x * blockDim.x;
    for (int i = blockIdx.x * blockDim.x + threadIdx.x; i < niter; i += stride) {
        int2 w = reinterpret_cast<const int2*>(x)[i];

        int gl = i >> 5;                       // group linear index (out_ch*64 + g)
        float s  = scale[gl];                  // fp32 (exactly fp16-representable)
        int zpw  = zp[gl >> 1];
        float zf = (float)((zpw >> ((gl & 1) << 2)) & 15);

        float4 o;
        // fp32 product of an fp16-representable scale and a <=5-bit int is
        // exact; one rounding to fp16 reproduces the reference's fp16 multiply.
        o.x = (float)(_Float16)(((float)( w.x        & 15) - zf) * s);
        o.y = (float)(_Float16)(((float)((w.x >> 4)  & 15) - zf) * s);
        o.z = (float)(_Float16)(((float)( w.y        & 15) - zf) * s);
        o.w = (float)(_Float16)(((float)((w.y >> 4)  & 15) - zf) * s);

        reinterpret_cast<float4*>(out)[i] = o;
    }
}

extern "C" void kernel_launch(void* const* d_in, const int* in_sizes, int n_in,
                              void* d_out, int out_size, void* d_ws, size_t ws_size,
                              hipStream_t stream) {
    const int*   x     = (const int*)d_in[0];
    const float* scale = (const float*)d_in[1];
    const int*   zp    = (const int*)d_in[2];
    float*       out   = (float*)d_out;

    const int niter = out_size / 4;   // 4 outputs per iteration = 16,777,216

    dim3 grid(2048), block(256);      // 8 blocks/CU, 32 waves/CU, grid-stride x32
    hipLaunchKernelGGL(int4_dequant_kernel, grid, block, 0, stream,
                       x, scale, zp, out, niter);
}